// Round 12
// baseline (456.957 us; speedup 1.0000x reference)
//
#include <hip/hip_runtime.h>
#include <math.h>

#define HW2 4096

typedef __attribute__((ext_vector_type(8))) short s16x8;
typedef __attribute__((ext_vector_type(4))) short s16x4;
typedef __attribute__((ext_vector_type(4))) float f32x4;
typedef __attribute__((ext_vector_type(4))) int i32x4;

__device__ __forceinline__ unsigned short f2bf(float x) {
  unsigned int u = __float_as_uint(x);
  u += 0x7fff + ((u >> 16) & 1);          // RNE
  return (unsigned short)(u >> 16);
}

__device__ __forceinline__ void async16(void* lds, const void* g) {
  __builtin_amdgcn_global_load_lds(
      (const __attribute__((address_space(1))) void*)g,
      (__attribute__((address_space(3))) void*)lds, 16, 0, 0);
}

// ---------------------------------------------------------------------------
// fp32 NCHW -> bf16 transposed [b][h][cc][w*32+ci].  Block = (cc, h8, b).
// ---------------------------------------------------------------------------
__global__ __launch_bounds__(256) void tpose_k(
    const float* __restrict__ in, unsigned short* __restrict__ outT, int CC)
{
  __shared__ short sT[32 * 534];
  const int cc = blockIdx.x;
  const int h0 = blockIdx.y * 8;
  const int b  = blockIdx.z;
  const int tid = threadIdx.x;
  const float* ip = in + (size_t)(b * CC + cc) * 32 * 4096;

  for (int e = tid; e < 4096; e += 256) {
    int ci = e >> 7, rem = e & 127;
    int h = rem >> 4, w4 = rem & 15;
    float4 v = *(const float4*)&ip[(size_t)ci * 4096 + (h0 + h) * 64 + w4 * 4];
    short* d = &sT[ci * 534 + h * 66 + w4 * 4];
    d[0] = (short)f2bf(v.x); d[1] = (short)f2bf(v.y);
    d[2] = (short)f2bf(v.z); d[3] = (short)f2bf(v.w);
  }
  __syncthreads();
  unsigned short* ob = outT + (size_t)b * 64 * CC * 2048;
  for (int e = tid; e < 2048; e += 256) {
    int h = e >> 8, rem = e & 255;
    int w = rem >> 2, q = rem & 3;
    s16x8 v;
    #pragma unroll
    for (int j = 0; j < 8; ++j) v[j] = sT[(q * 8 + j) * 534 + h * 66 + w];
    *(s16x8*)&ob[((size_t)(h0 + h) * CC + cc) * 2048 + w * 32 + q * 8] = v;
  }
}

// ---------------------------------------------------------------------------
// Weight prep (coalesced): fp32 OIHW -> bf16 MFMA A-frag order.
// ---------------------------------------------------------------------------
__global__ __launch_bounds__(256) void wprep_k(const float* __restrict__ w,
                                               unsigned short* __restrict__ Wb,
                                               int Cin) {
  __shared__ float sC[32 * 289];
  const int CC = Cin >> 5;
  const int cc = blockIdx.x % CC, cob = blockIdx.x / CC;
  const int tid = threadIdx.x;
  for (int e = tid; e < 2304; e += 256) {
    int co = e / 72, off = e % 72;
    float4 v = *(const float4*)&w[((size_t)(cob * 32 + co) * Cin + cc * 32) * 9 +
                                  off * 4];
    float* d = &sC[co * 289 + off * 4];
    d[0] = v.x; d[1] = v.y; d[2] = v.z; d[3] = v.w;
  }
  __syncthreads();
  unsigned short* ob = Wb + (size_t)(cob * CC + cc) * 9216;
  for (int e = tid; e < 1152; e += 256) {
    int ln = e & 15, q = (e >> 4) & 3, mt = (e >> 6) & 1, t = e >> 7;
    s16x8 v;
    #pragma unroll
    for (int j = 0; j < 8; ++j)
      v[j] = (short)f2bf(sC[(mt * 16 + ln) * 289 + (q * 8 + j) * 9 + t]);
    *(s16x8*)&ob[(size_t)e * 8] = v;
  }
}

// ---------------------------------------------------------------------------
// Head weight prep: fp32 (81,256) -> bf16 A-frag order [kk][mt][lane][8].
// Rows 81..95 zero-padded.  3072 lane-frags total.
// NOTE: launched AFTER the last bufA consumer in the fast path (round-2 bug).
// ---------------------------------------------------------------------------
__global__ __launch_bounds__(256) void wprep3_k(const float* __restrict__ w3,
                                                unsigned short* __restrict__ w3b)
{
  const int tid = threadIdx.x + blockIdx.x * 256;
  if (tid >= 3072) return;
  const int kk = tid / 384, r = tid % 384;
  const int mt = r >> 6, lane = r & 63;
  const int ln = lane & 15, q = lane >> 4;
  const int co = mt * 16 + ln;
  s16x8 v;
  #pragma unroll
  for (int j = 0; j < 8; ++j)
    v[j] = (co < 81) ? (short)f2bf(w3[co * 256 + kk * 32 + q * 8 + j]) : (short)0;
  *(s16x8*)&w3b[(size_t)tid * 8] = v;
}

// ---------------------------------------------------------------------------
// 3x3 conv + bias + relu via MFMA bf16 implicit GEMM.
// ---------------------------------------------------------------------------
template <int SRC_BF16, int EPI_BF16>
__global__ __launch_bounds__(256, 3) void conv_mfma_k(
    const void* __restrict__ inp,
    const unsigned short* __restrict__ Wb,
    const float* __restrict__ bias,
    void* __restrict__ outp,
    int CC, int occ0, int outCC)
{
  __shared__ short sIn[6 * 66 * 32];   // 25344 B
  __shared__ short sW[9216];           // 18432 B

  const int tid = threadIdx.x;
  const int lane = tid & 63;
  const int wid = tid >> 6;
  const int ln = lane & 15;
  const int q = lane >> 4;
  const int w0 = wid * 16;
  const int pb = blockIdx.x;
  const int b = pb >> 4;
  const int h0 = (pb & 15) * 4;
  const int cob = blockIdx.y;

  if (tid < 48) {
    int r = tid >> 3, side = (tid >> 2) & 1, qq = tid & 3;
    int col = side ? 65 : 0;
    s16x8 z = (s16x8)0;
    *(s16x8*)&sIn[(r * 66 + col) * 32 + qq * 8] = z;
  }
  if (SRC_BF16) {
    #pragma unroll
    for (int r = 0; r < 6; ++r) {
      int h = h0 - 1 + r;
      if (h < 0 || h > 63) {
        s16x8 z = (s16x8)0;
        *(s16x8*)&sIn[(r * 66 + 1) * 32 + tid * 8] = z;
      }
    }
  }

  f32x4 acc[2][4];
  #pragma unroll
  for (int mt = 0; mt < 2; ++mt)
    #pragma unroll
    for (int r = 0; r < 4; ++r) acc[mt][r] = (f32x4){0.f, 0.f, 0.f, 0.f};

  for (int cc = 0; cc < CC; ++cc) {
    {
      const unsigned short* gw = Wb + (size_t)(cob * CC + cc) * 9216;
      for (int s = wid; s < 18; s += 4)
        async16(&sW[s * 512 + lane * 8], gw + s * 512 + lane * 8);
    }
    if (SRC_BF16) {
      const unsigned short* cat = (const unsigned short*)inp;
      #pragma unroll
      for (int k = 0; k < 6; ++k) {
        int h = h0 - 1 + k;
        if (h >= 0 && h <= 63) {
          const unsigned short* gsrc =
              cat + ((size_t)(b * 64 + h) * CC + cc) * 2048 + wid * 512 + lane * 8;
          async16(&sIn[(k * 66 + 1) * 32 + wid * 512 + lane * 8], gsrc);
        }
      }
    } else {
      const float* fin = (const float*)inp;
      const int sq = tid & 3, sw = tid >> 2;
      #pragma unroll
      for (int r = 0; r < 6; ++r) {
        int h = h0 - 1 + r;
        s16x8 v;
        if (h >= 0 && h <= 63) {
          #pragma unroll
          for (int k = 0; k < 8; ++k) {
            float val = fin[((size_t)(b * (CC * 32) + cc * 32 + sq * 8 + k) << 12) +
                            h * 64 + sw];
            v[k] = (short)f2bf(val);
          }
        } else {
          v = (s16x8)0;
        }
        *(s16x8*)&sIn[(r * 66 + sw + 1) * 32 + sq * 8] = v;
      }
    }
    __syncthreads();
    #pragma unroll
    for (int kw = 0; kw < 3; ++kw) {
      s16x8 Bfr[6];
      #pragma unroll
      for (int rp = 0; rp < 6; ++rp)
        Bfr[rp] = *(const s16x8*)&sIn[(rp * 66 + w0 + kw + ln) * 32 + q * 8];
      #pragma unroll
      for (int kh = 0; kh < 3; ++kh) {
        #pragma unroll
        for (int mt = 0; mt < 2; ++mt) {
          s16x8 Afr = *(const s16x8*)&sW[((kh * 3 + kw) * 2 + mt) * 512 + lane * 8];
          #pragma unroll
          for (int r = 0; r < 4; ++r)
            acc[mt][r] = __builtin_amdgcn_mfma_f32_16x16x32_bf16(
                Afr, Bfr[r + kh], acc[mt][r], 0, 0, 0);
        }
      }
    }
    __syncthreads();
  }

  #pragma unroll
  for (int mt = 0; mt < 2; ++mt) {
    const float4 bv = *(const float4*)&bias[cob * 32 + mt * 16 + q * 4];
    #pragma unroll
    for (int r = 0; r < 4; ++r) {
      float y0 = fmaxf(acc[mt][r].x + bv.x, 0.f);
      float y1 = fmaxf(acc[mt][r].y + bv.y, 0.f);
      float y2 = fmaxf(acc[mt][r].z + bv.z, 0.f);
      float y3 = fmaxf(acc[mt][r].w + bv.w, 0.f);
      if (EPI_BF16) {
        s16x4 pk;
        pk[0] = (short)f2bf(y0); pk[1] = (short)f2bf(y1);
        pk[2] = (short)f2bf(y2); pk[3] = (short)f2bf(y3);
        unsigned short* ob = (unsigned short*)outp;
        size_t off = ((size_t)(b * 64 + h0 + r) * outCC + (occ0 + cob)) * 2048 +
                     (w0 + ln) * 32 + mt * 16 + q * 4;
        *(s16x4*)&ob[off] = pk;
      } else {
        float* ob = (float*)outp;
        int co = cob * 32 + mt * 16 + q * 4;
        size_t base = ((size_t)b * outCC + co) * HW2 + (h0 + r) * 64 + w0 + ln;
        ob[base] = y0;
        ob[base + HW2] = y1;
        ob[base + 2 * HW2] = y2;
        ob[base + 3 * HW2] = y3;
      }
    }
  }
}

// ---------------------------------------------------------------------------
// 1x1 head (256->81) + bias + relu + softmax via MFMA.  Block = (b,h) row,
// 4 waves = 4 w-tiles of 16.  No LDS, no barriers.
// ---------------------------------------------------------------------------
__global__ __launch_bounds__(256) void head_mfma_k(
    const unsigned short* __restrict__ x2b, const unsigned short* __restrict__ w3b,
    const float* __restrict__ b3, float* __restrict__ kern)
{
  const int bh = blockIdx.x;
  const int b = bh >> 6, h = bh & 63;
  const int tid = threadIdx.x;
  const int lane = tid & 63;
  const int wid = tid >> 6;
  const int ln = lane & 15, q = lane >> 4;
  const int w0 = wid * 16;

  f32x4 acc[6];
  #pragma unroll
  for (int mt = 0; mt < 6; ++mt) acc[mt] = (f32x4){0.f, 0.f, 0.f, 0.f};

  const unsigned short* xrow = x2b + (size_t)(b * 64 + h) * 8 * 2048;
  #pragma unroll
  for (int kk = 0; kk < 8; ++kk) {
    s16x8 Bfr = *(const s16x8*)&xrow[kk * 2048 + (w0 + ln) * 32 + q * 8];
    #pragma unroll
    for (int mt = 0; mt < 6; ++mt) {
      s16x8 Afr = *(const s16x8*)&w3b[(size_t)((kk * 6 + mt) * 64 + lane) * 8];
      acc[mt] = __builtin_amdgcn_mfma_f32_16x16x32_bf16(Afr, Bfr, acc[mt], 0, 0, 0);
    }
  }

  // bias + relu (co = mt*16 + q*4 + r; valid co < 81)
  float vv[20];
  #pragma unroll
  for (int mt = 0; mt < 5; ++mt)
    #pragma unroll
    for (int r = 0; r < 4; ++r)
      vv[mt * 4 + r] = fmaxf(acc[mt][r] + b3[mt * 16 + q * 4 + r], 0.f);
  float v80 = fmaxf(acc[5][0] + b3[80], 0.f);   // valid only when q==0

  float m = vv[0];
  #pragma unroll
  for (int k = 1; k < 20; ++k) m = fmaxf(m, vv[k]);
  if (q == 0) m = fmaxf(m, v80);
  m = fmaxf(m, __shfl_xor(m, 16));
  m = fmaxf(m, __shfl_xor(m, 32));

  float e[20], e80 = 0.f, s = 0.f;
  #pragma unroll
  for (int k = 0; k < 20; ++k) { e[k] = __expf(vv[k] - m); s += e[k]; }
  if (q == 0) { e80 = __expf(v80 - m); s += e80; }
  s += __shfl_xor(s, 16);
  s += __shfl_xor(s, 32);
  const float rr = 1.f / s;

  float* kp = kern + (size_t)(b * 81) * HW2 + h * 64 + w0 + ln;
  #pragma unroll
  for (int mt = 0; mt < 5; ++mt)
    #pragma unroll
    for (int r = 0; r < 4; ++r)
      kp[(size_t)(mt * 16 + q * 4 + r) * HW2] = e[mt * 4 + r] * rr;
  if (q == 0) kp[(size_t)80 * HW2] = e80 * rr;
}

// ---------------------------------------------------------------------------
// Spatially-variant conv, v9: double-buffered LDS row pipeline, ONE barrier
// per iteration, rolled loop (round-11 lesson: rolled keeps VGPR sane).
// Round-11 forensics: k8 worked (VGPR 64, 70us) but VALUBusy 45% — the
// stage(i+1) was issued after the mid-iter barrier, leaving only ~288 FMA
// cycles to cover ~550cy L3 latency -> ~250cy drain stall at each top
// barrier.  v9 shrinks the kern buffer to the CURRENT row's 9 taps
// (2.25KB, async16-staged per iter like sF), so dbuf fits in the same
// 37.4KB (4 blocks/CU), and the stage is issued right after the single
// barrier -> ~450+cy of cover.  Vertically-OOB rows are SKIPPED entirely
// (block-uniform branch; reference zero-pads so their contribution is 0)
// -> no tap zeroing, no sF zero-init, fewer iterations on edge blocks.
// ---------------------------------------------------------------------------
__global__ __launch_bounds__(256) void svc_k9(
    const float* __restrict__ feats, const float* __restrict__ kern,
    float* __restrict__ out)
{
  __shared__ __align__(16) float sF[2][64 * 64 + 4];  // 2x16400 B (+4 = zeros)
  __shared__ __align__(16) float sKr[2][9 * 64];      // 2x2304 B
  const int b = blockIdx.z, h = blockIdx.y, cb = blockIdx.x * 64;
  const int tid = threadIdx.x;

  // zero the two 4-float pads (never overwritten: stage writes idx 0..4095)
  if (tid < 8) sF[tid >> 2][4096 + (tid & 3)] = 0.f;

  const int wq = tid & 15, cs = tid >> 4;
  const int w0 = wq * 4;

  // valid tap-row range: hh = h-4+i in [0,63]
  const int i0 = (h < 4) ? 4 - h : 0;
  const int i1 = (h > 59) ? 67 - h : 8;

  // i-invariant LDS read indices (floats within one sF buffer);
  // w-edge lanes -> the zero pad at 4096
  int aL[4], aM[4], aR[4];
  #pragma unroll
  for (int ch = 0; ch < 4; ++ch) {
    int base = (cs * 4 + ch) * 64 + w0;
    aM[ch] = base;
    aL[ch] = wq ? (base - 4) : 4096;
    aR[ch] = (wq != 15) ? (base + 4) : 4096;
  }

  // stage sources.  sF: chunk = s*256+tid -> ch = s*16+(tid>>4), wquad=tid&15
  const float* gF = feats + (((size_t)(b * 1024 + cb + (tid >> 4))) << 12) +
                    (tid & 15) * 4;
  // sKr: chunk c = tid (<144): tap-in-row = c>>4 (0..8), wquad = c&15
  const float* gK = kern + ((size_t)(b * 81) + (tid >> 4)) * HW2 + h * 64 +
                    (tid & 15) * 4;

  // prologue: stage row i0 into buffer 0
  {
    int hh = h - 4 + i0;
    #pragma unroll
    for (int s = 0; s < 4; ++s)
      async16((char*)&sF[0][0] + (size_t)(s * 256 + tid) * 16,
              gF + (size_t)s * 65536 + hh * 64);
    if (tid < 144)
      async16((char*)&sKr[0][0] + (size_t)tid * 16,
              gK + (size_t)(i0 * 9) * HW2);
  }

  f32x4 acc[4];
  #pragma unroll
  for (int ch = 0; ch < 4; ++ch) acc[ch] = (f32x4){0.f, 0.f, 0.f, 0.f};

  int bb = 0;
  #pragma unroll 1
  for (int i = i0; i <= i1; ++i) {
    __syncthreads();   // stage into buf bb (row i) complete; prior reads done
    if (i < i1) {      // issue next-row stage into buf bb^1
      int hh = h - 4 + i + 1;
      #pragma unroll
      for (int s = 0; s < 4; ++s)
        async16((char*)&sF[bb ^ 1][0] + (size_t)(s * 256 + tid) * 16,
                gF + (size_t)s * 65536 + hh * 64);
      if (tid < 144)
        async16((char*)&sKr[bb ^ 1][0] + (size_t)tid * 16,
                gK + (size_t)((i + 1) * 9) * HW2);
    }
    const float* fb = &sF[bb][0];
    float f[4][12];
    #pragma unroll
    for (int ch = 0; ch < 4; ++ch) {
      f32x4 L = *(const f32x4*)&fb[aL[ch]];
      f32x4 M = *(const f32x4*)&fb[aM[ch]];
      f32x4 R = *(const f32x4*)&fb[aR[ch]];
      f[ch][0] = L[0]; f[ch][1] = L[1]; f[ch][2]  = L[2]; f[ch][3]  = L[3];
      f[ch][4] = M[0]; f[ch][5] = M[1]; f[ch][6]  = M[2]; f[ch][7]  = M[3];
      f[ch][8] = R[0]; f[ch][9] = R[1]; f[ch][10] = R[2]; f[ch][11] = R[3];
    }
    const float* krow = &sKr[bb][w0];
    #pragma unroll
    for (int j = 0; j < 9; ++j) {
      const f32x4 kv = *(const f32x4*)&krow[j * 64];
      #pragma unroll
      for (int ch = 0; ch < 4; ++ch) {
        acc[ch][0] += f[ch][j]     * kv[0];
        acc[ch][1] += f[ch][j + 1] * kv[1];
        acc[ch][2] += f[ch][j + 2] * kv[2];
        acc[ch][3] += f[ch][j + 3] * kv[3];
      }
    }
    bb ^= 1;
  }

  #pragma unroll
  for (int ch = 0; ch < 4; ++ch)
    *(f32x4*)&out[((size_t)(b * 1024 + cb + cs * 4 + ch)) * HW2 + h * 64 + w0] =
        acc[ch];
}

// ---------------------------------------------------------------------------
extern "C" void kernel_launch(void* const* d_in, const int* in_sizes, int n_in,
                              void* d_out, int out_size, void* d_ws, size_t ws_size,
                              hipStream_t stream) {
  const float* cur  = (const float*)d_in[0];
  const float* keyl = (const float*)d_in[1];
  const float* keyh = (const float*)d_in[2];
  const float* w_r  = (const float*)d_in[3];
  const float* b_r  = (const float*)d_in[4];
  const float* w2   = (const float*)d_in[5];
  const float* b2   = (const float*)d_in[6];
  const float* w3   = (const float*)d_in[7];
  const float* b3   = (const float*)d_in[8];
  float* out = (float*)d_out;
  char* ws = (char*)d_ws;

  const size_t NEED_FAST = 57409536;
  if (ws_size >= NEED_FAST) {
    // fast path layout:
    //   cat 16.78MB | Wb1 4.72MB | Wb2 2.36MB | bufA 33.55MB [23855104,57409536)
    //   After the conv1 pair, bufA is dead; x2b [23855104,32243712),
    //   kern [40632320,45940736) and w3b [45940736,45989888) overlay it.
    //   wprep3_k MUST launch after the last bufA consumer (round-2 bug).
    unsigned short* cat  = (unsigned short*)ws;
    unsigned short* Wb1  = (unsigned short*)(ws + 16777216);
    unsigned short* Wb2  = (unsigned short*)(ws + 21495808);
    unsigned short* bufA = (unsigned short*)(ws + 23855104);
    unsigned short* x2b  = (unsigned short*)(ws + 23855104);
    float*          kern = (float*)(ws + 40632320);
    unsigned short* w3b  = (unsigned short*)(ws + 45940736);

    wprep_k<<<256, 256, 0, stream>>>(w_r, Wb1, 1024);
    wprep_k<<<128, 256, 0, stream>>>(w2,  Wb2, 512);

    tpose_k<<<dim3(32, 8, 4), 256, 0, stream>>>(cur, bufA, 32);
    conv_mfma_k<1, 1><<<dim3(64, 8), 256, 0, stream>>>(bufA, Wb1, b_r, cat, 32, 0, 16);
    tpose_k<<<dim3(32, 8, 4), 256, 0, stream>>>(keyl, bufA, 32);
    conv_mfma_k<1, 1><<<dim3(64, 8), 256, 0, stream>>>(bufA, Wb1, b_r, cat, 32, 8, 16);

    wprep3_k<<<12, 256, 0, stream>>>(w3, w3b);   // bufA dead from here on

    conv_mfma_k<1, 1><<<dim3(64, 8), 256, 0, stream>>>(cat, Wb2, b2, x2b, 16, 0, 8);

    head_mfma_k<<<256, 256, 0, stream>>>(x2b, w3b, b3, kern);
    svc_k9<<<dim3(16, 64, 4), 256, 0, stream>>>(keyh, kern, out);
  } else {
    // fallback (37.6MB): fp32-NCHW staged convs, same MFMA head (no overlap)
    unsigned short* cat  = (unsigned short*)ws;
    unsigned short* x2b  = (unsigned short*)(ws + 16777216);
    float*          kern = (float*)(ws + 25165824);
    unsigned short* Wb1  = (unsigned short*)(ws + 30474240);
    unsigned short* Wb2  = (unsigned short*)(ws + 35192832);
    unsigned short* w3b  = (unsigned short*)(ws + 37552128);

    wprep_k<<<256, 256, 0, stream>>>(w_r, Wb1, 1024);
    wprep_k<<<128, 256, 0, stream>>>(w2,  Wb2, 512);
    wprep3_k<<<12, 256, 0, stream>>>(w3, w3b);

    conv_mfma_k<0, 1><<<dim3(64, 8), 256, 0, stream>>>(cur,  Wb1, b_r, cat, 32, 0, 16);
    conv_mfma_k<0, 1><<<dim3(64, 8), 256, 0, stream>>>(keyl, Wb1, b_r, cat, 32, 8, 16);
    conv_mfma_k<1, 1><<<dim3(64, 8), 256, 0, stream>>>(cat,  Wb2, b2, x2b, 16, 0, 8);

    head_mfma_k<<<256, 256, 0, stream>>>(x2b, w3b, b3, kern);
    svc_k9<<<dim3(16, 64, 4), 256, 0, stream>>>(keyh, kern, out);
  }
}